// Round 1
// baseline (1995.759 us; speedup 1.0000x reference)
//
#include <hip/hip_runtime.h>

// ---------------- problem constants ----------------
constexpr int Bg  = 8;       // graphs
constexpr int Nn  = 1024;    // nodes per graph
constexpr int Cc  = 256;     // channels
constexpr int Hh  = 8;       // heads
constexpr int DK  = 32;      // head dim
constexpr int Ee  = 131072;  // edges
constexpr int BNn = Bg * Nn; // 8192 total nodes
#define EPSV 1e-5f

// ---------------- generic tiled GEMM ----------------
// out[M,N] = maybe_relu( A[M,K] @ W[K,N] + bias? + add1? + add2? )
// 64x64 tile per block, 256 threads, 4x4 per thread, BK=16.
__global__ __launch_bounds__(256) void gemm_k(
    const float* __restrict__ A, const float* __restrict__ W,
    const float* __restrict__ bias, const float* __restrict__ add1,
    const float* __restrict__ add2, float* __restrict__ out,
    int M, int K, int N, int relu)
{
    __shared__ float As[64][17];  // +1 pad: avoid 4-way bank conflict on column reads
    __shared__ float Ws[16][65];

    const int t  = threadIdx.x;
    const int tm = (t >> 4) << 2;   // 0..60 step 4
    const int tn = (t & 15) << 2;   // 0..60 step 4
    const int m0 = blockIdx.y * 64;
    const int n0 = blockIdx.x * 64;

    float acc[4][4] = {};

    for (int k0 = 0; k0 < K; k0 += 16) {
        #pragma unroll
        for (int i = 0; i < 4; ++i) {
            int lin = t + i * 256;           // 0..1023
            int m = lin >> 4, k = lin & 15;
            As[m][k] = A[(size_t)(m0 + m) * K + k0 + k];
        }
        #pragma unroll
        for (int i = 0; i < 4; ++i) {
            int lin = t + i * 256;
            int k = lin >> 6, n = lin & 63;
            Ws[k][n] = W[(size_t)(k0 + k) * N + n0 + n];
        }
        __syncthreads();
        #pragma unroll
        for (int kk = 0; kk < 16; ++kk) {
            float a[4], b[4];
            #pragma unroll
            for (int i = 0; i < 4; ++i) a[i] = As[tm + i][kk];
            #pragma unroll
            for (int j = 0; j < 4; ++j) b[j] = Ws[kk][tn + j];
            #pragma unroll
            for (int i = 0; i < 4; ++i)
                #pragma unroll
                for (int j = 0; j < 4; ++j)
                    acc[i][j] += a[i] * b[j];
        }
        __syncthreads();
    }

    #pragma unroll
    for (int i = 0; i < 4; ++i) {
        int row = m0 + tm + i;
        #pragma unroll
        for (int j = 0; j < 4; ++j) {
            int col = n0 + tn + j;
            float v = acc[i][j];
            if (bias) v += bias[col];
            size_t idx = (size_t)row * N + col;
            if (add1) v += add1[idx];
            if (add2) v += add2[idx];
            if (relu) v = fmaxf(v, 0.f);
            out[idx] = v;
        }
    }
}

// ---------------- edge scatter: agg[dst] += xWn[src] ----------------
__global__ __launch_bounds__(256) void scatter_k(
    const float* __restrict__ xWn, const int* __restrict__ ei,
    float* __restrict__ agg)
{
    int e = blockIdx.x;
    int c = threadIdx.x;
    int s = ei[e];
    int d = ei[Ee + e];
    atomicAdd(&agg[(size_t)d * Cc + c], xWn[(size_t)s * Cc + c]);
}

// ---------------- BN stats: per-channel sum & sumsq ----------------
__global__ __launch_bounds__(256) void bn_stats_k(
    const float* __restrict__ h, float* __restrict__ gsum, float* __restrict__ gsq)
{
    int ch = threadIdx.x;
    int r0 = blockIdx.x * 32;
    float s = 0.f, s2 = 0.f;
    for (int r = r0; r < r0 + 32; ++r) {
        float v = h[(size_t)r * Cc + ch];
        s += v; s2 += v * v;
    }
    atomicAdd(&gsum[ch], s);
    atomicAdd(&gsq[ch], s2);
}

// ---------------- BN apply: out = bn(h)*g + b + add? ----------------
__global__ __launch_bounds__(256) void bn_apply_k(
    const float* __restrict__ h, const float* __restrict__ gsum,
    const float* __restrict__ gsq, const float* __restrict__ gamma,
    const float* __restrict__ beta, const float* __restrict__ add,
    float* __restrict__ out)
{
    size_t idx = (size_t)blockIdx.x * 256 + threadIdx.x;  // over BNn*Cc
    int ch = (int)(idx & (Cc - 1));
    float m   = gsum[ch] * (1.f / BNn);
    float var = gsq[ch] * (1.f / BNn) - m * m;
    float sc  = rsqrtf(var + EPSV) * gamma[ch];
    float v = (h[idx] - m) * sc + beta[ch];
    if (add) v += add[idx];
    out[idx] = v;
}

// ---------------- attention: one block per (b,h,n) ----------------
__global__ __launch_bounds__(256) void attn_k(
    const float* __restrict__ q, const float* __restrict__ k,
    const float* __restrict__ v, const float* __restrict__ sph,
    float* __restrict__ o)
{
    const int n = blockIdx.x, h = blockIdx.y, b = blockIdx.z;
    const int t = threadIdx.x;
    __shared__ float qs[DK];
    __shared__ float sc[Nn];
    __shared__ float red[256];
    const float scale = 0.17677669529663687f;  // 1/sqrt(32)

    if (t < DK) qs[t] = q[((size_t)(b * Nn + n)) * Cc + h * DK + t];
    __syncthreads();

    // scores + local max
    float lmax = -1e30f;
    for (int m = t; m < Nn; m += 256) {
        const float* kr = k + ((size_t)(b * Nn + m)) * Cc + h * DK;
        float dot = 0.f;
        #pragma unroll
        for (int d2 = 0; d2 < DK; ++d2) dot += qs[d2] * kr[d2];
        float s = dot * scale * sph[((size_t)b * Nn + n) * Nn + m];
        sc[m] = s;
        lmax = fmaxf(lmax, s);
    }
    red[t] = lmax; __syncthreads();
    for (int off = 128; off > 0; off >>= 1) {
        if (t < off) red[t] = fmaxf(red[t], red[t + off]);
        __syncthreads();
    }
    float mx = red[0]; __syncthreads();

    // exp + sum
    float lsum = 0.f;
    for (int m = t; m < Nn; m += 256) {
        float e = __expf(sc[m] - mx);
        sc[m] = e;
        lsum += e;
    }
    red[t] = lsum; __syncthreads();
    for (int off = 128; off > 0; off >>= 1) {
        if (t < off) red[t] += red[t + off];
        __syncthreads();
    }
    float inv = 1.f / red[0]; __syncthreads();

    // o[d] = sum_m p[m] * v[m,d] ; 8 m-groups x 32 d-lanes
    const int d = t & 31, g = t >> 5;
    float acc = 0.f;
    for (int m = g; m < Nn; m += 8)
        acc += sc[m] * v[((size_t)(b * Nn + m)) * Cc + h * DK + d];
    red[t] = acc; __syncthreads();
    if (t < 32) {
        float s = 0.f;
        #pragma unroll
        for (int gg = 0; gg < 8; ++gg) s += red[gg * 32 + t];
        o[((size_t)(b * Nn + n)) * Cc + h * DK + t] = s * inv;
    }
}

// ---------------- launch ----------------
extern "C" void kernel_launch(void* const* d_in, const int* in_sizes, int n_in,
                              void* d_out, int out_size, void* d_ws, size_t ws_size,
                              hipStream_t stream)
{
    const float* x   = (const float*)d_in[0];
    const int*   ei  = (const int*)  d_in[1];
    const float* sph = (const float*)d_in[2];
    const float* Wr  = (const float*)d_in[3];
    const float* Wn  = (const float*)d_in[4];
    const float* Wq  = (const float*)d_in[5];
    const float* bq  = (const float*)d_in[6];
    const float* Wk  = (const float*)d_in[7];
    const float* bk  = (const float*)d_in[8];
    const float* Wv  = (const float*)d_in[9];
    const float* bv  = (const float*)d_in[10];
    const float* Wo  = (const float*)d_in[11];
    const float* bo  = (const float*)d_in[12];
    const float* W1  = (const float*)d_in[13];
    const float* b1  = (const float*)d_in[14];
    const float* W2  = (const float*)d_in[15];
    const float* b2  = (const float*)d_in[16];
    const float* g1  = (const float*)d_in[17];
    const float* be1 = (const float*)d_in[18];
    const float* g2  = (const float*)d_in[19];
    const float* be2 = (const float*)d_in[20];
    const float* g3  = (const float*)d_in[21];
    const float* be3 = (const float*)d_in[22];
    float* out = (float*)d_out;

    const size_t SL = (size_t)BNn * Cc;  // 2M floats
    float* ws = (float*)d_ws;
    float* s0 = ws;
    float* s1 = ws + SL;
    float* s2 = ws + 2 * SL;
    float* s3 = ws + 3 * SL;
    float* s4 = ws + 4 * SL;
    float* hid = ws + 5 * SL;            // 4M floats (8192 x 512)
    float* stats = ws + 7 * SL;          // 512 floats (sum | sumsq)

    dim3 gB(4, 128);   // N=256 tiles x M=8192 tiles
    dim3 gB512(8, 128);

    // 1) xWn = x @ Wn
    gemm_k<<<gB, 256, 0, stream>>>(x, Wn, nullptr, nullptr, nullptr, s0, BNn, Cc, Cc, 0);
    // 2) agg = segment_sum(xWn[src], dst)
    hipMemsetAsync(s1, 0, SL * sizeof(float), stream);
    scatter_k<<<Ee, 256, 0, stream>>>(s0, ei, s1);
    // 3) h1pre = x @ Wr + agg + x
    gemm_k<<<gB, 256, 0, stream>>>(x, Wr, nullptr, s1, x, s2, BNn, Cc, Cc, 0);
    // 4) h1 = BN1(h1pre)  -> s3
    hipMemsetAsync(stats, 0, 512 * sizeof(float), stream);
    bn_stats_k<<<256, 256, 0, stream>>>(s2, stats, stats + 256);
    bn_apply_k<<<BNn, 256, 0, stream>>>(s2, stats, stats + 256, g1, be1, nullptr, s3);
    // 5) q,k,v projections
    gemm_k<<<gB, 256, 0, stream>>>(x, Wq, bq, nullptr, nullptr, s0, BNn, Cc, Cc, 0);
    gemm_k<<<gB, 256, 0, stream>>>(x, Wk, bk, nullptr, nullptr, s1, BNn, Cc, Cc, 0);
    gemm_k<<<gB, 256, 0, stream>>>(x, Wv, bv, nullptr, nullptr, s2, BNn, Cc, Cc, 0);
    // 6) attention -> s4  (o in [b,n,h,dk] = [BNn, Cc] layout)
    attn_k<<<dim3(Nn, Hh, Bg), 256, 0, stream>>>(s0, s1, s2, sph, s4);
    // 7) h2pre = o @ Wo + bo + x -> s0
    gemm_k<<<gB, 256, 0, stream>>>(s4, Wo, bo, x, nullptr, s0, BNn, Cc, Cc, 0);
    // 8) outsum = BN2(h2pre) + h1 -> s1
    hipMemsetAsync(stats, 0, 512 * sizeof(float), stream);
    bn_stats_k<<<256, 256, 0, stream>>>(s0, stats, stats + 256);
    bn_apply_k<<<BNn, 256, 0, stream>>>(s0, stats, stats + 256, g2, be2, s3, s1);
    // 9) hidden = relu(outsum @ W1 + b1)
    gemm_k<<<gB512, 256, 0, stream>>>(s1, W1, b1, nullptr, nullptr, hid, BNn, Cc, 2 * Cc, 1);
    // 10) out2 = hidden @ W2 + b2 + outsum -> s2
    gemm_k<<<gB, 256, 0, stream>>>(hid, W2, b2, s1, nullptr, s2, BNn, 2 * Cc, Cc, 0);
    // 11) d_out = BN3(out2)
    hipMemsetAsync(stats, 0, 512 * sizeof(float), stream);
    bn_stats_k<<<256, 256, 0, stream>>>(s2, stats, stats + 256);
    bn_apply_k<<<BNn, 256, 0, stream>>>(s2, stats, stats + 256, g3, be3, nullptr, out);
}

// Round 2
// 872.149 us; speedup vs baseline: 2.2883x; 2.2883x over previous
//
#include <hip/hip_runtime.h>

// ---------------- problem constants ----------------
constexpr int Bg  = 8;       // graphs
constexpr int Nn  = 1024;    // nodes per graph
constexpr int Cc  = 256;     // channels
constexpr int Hh  = 8;       // heads
constexpr int DK  = 32;      // head dim
constexpr int Ee  = 131072;  // edges
constexpr int BNn = Bg * Nn; // 8192 total nodes
#define EPSV 1e-5f

// ---------------- generic tiled GEMM ----------------
// out[M,N] = maybe_relu( A[M,K] @ W[K,N] + bias? + add1? + add2? )
// 64x64 tile per block, 256 threads, 4x4 per thread, BK=16.
__global__ __launch_bounds__(256) void gemm_k(
    const float* __restrict__ A, const float* __restrict__ W,
    const float* __restrict__ bias, const float* __restrict__ add1,
    const float* __restrict__ add2, float* __restrict__ out,
    int M, int K, int N, int relu)
{
    __shared__ float As[64][17];
    __shared__ float Ws[16][65];

    const int t  = threadIdx.x;
    const int tm = (t >> 4) << 2;
    const int tn = (t & 15) << 2;
    const int m0 = blockIdx.y * 64;
    const int n0 = blockIdx.x * 64;

    float acc[4][4] = {};

    for (int k0 = 0; k0 < K; k0 += 16) {
        #pragma unroll
        for (int i = 0; i < 4; ++i) {
            int lin = t + i * 256;
            int m = lin >> 4, k = lin & 15;
            As[m][k] = A[(size_t)(m0 + m) * K + k0 + k];
        }
        #pragma unroll
        for (int i = 0; i < 4; ++i) {
            int lin = t + i * 256;
            int k = lin >> 6, n = lin & 63;
            Ws[k][n] = W[(size_t)(k0 + k) * N + n0 + n];
        }
        __syncthreads();
        #pragma unroll
        for (int kk = 0; kk < 16; ++kk) {
            float a[4], b[4];
            #pragma unroll
            for (int i = 0; i < 4; ++i) a[i] = As[tm + i][kk];
            #pragma unroll
            for (int j = 0; j < 4; ++j) b[j] = Ws[kk][tn + j];
            #pragma unroll
            for (int i = 0; i < 4; ++i)
                #pragma unroll
                for (int j = 0; j < 4; ++j)
                    acc[i][j] += a[i] * b[j];
        }
        __syncthreads();
    }

    #pragma unroll
    for (int i = 0; i < 4; ++i) {
        int row = m0 + tm + i;
        #pragma unroll
        for (int j = 0; j < 4; ++j) {
            int col = n0 + tn + j;
            float v = acc[i][j];
            if (bias) v += bias[col];
            size_t idx = (size_t)row * N + col;
            if (add1) v += add1[idx];
            if (add2) v += add2[idx];
            if (relu) v = fmaxf(v, 0.f);
            out[idx] = v;
        }
    }
}

// ---------------- edge scatter: agg[dst] += xWn[src] ----------------
__global__ __launch_bounds__(256) void scatter_k(
    const float* __restrict__ xWn, const int* __restrict__ ei,
    float* __restrict__ agg)
{
    int e = blockIdx.x;
    int c = threadIdx.x;
    int s = ei[e];
    int d = ei[Ee + e];
    atomicAdd(&agg[(size_t)d * Cc + c], xWn[(size_t)s * Cc + c]);
}

// ---------------- BN stats: per-channel sum & sumsq ----------------
__global__ __launch_bounds__(256) void bn_stats_k(
    const float* __restrict__ h, float* __restrict__ gsum, float* __restrict__ gsq)
{
    int ch = threadIdx.x;
    int r0 = blockIdx.x * 32;
    float s = 0.f, s2 = 0.f;
    for (int r = r0; r < r0 + 32; ++r) {
        float v = h[(size_t)r * Cc + ch];
        s += v; s2 += v * v;
    }
    atomicAdd(&gsum[ch], s);
    atomicAdd(&gsq[ch], s2);
}

// ---------------- BN apply: out = bn(h)*g + b + add? ----------------
__global__ __launch_bounds__(256) void bn_apply_k(
    const float* __restrict__ h, const float* __restrict__ gsum,
    const float* __restrict__ gsq, const float* __restrict__ gamma,
    const float* __restrict__ beta, const float* __restrict__ add,
    float* __restrict__ out)
{
    size_t idx = (size_t)blockIdx.x * 256 + threadIdx.x;
    int ch = (int)(idx & (Cc - 1));
    float m   = gsum[ch] * (1.f / BNn);
    float var = gsq[ch] * (1.f / BNn) - m * m;
    float sc  = rsqrtf(var + EPSV) * gamma[ch];
    float v = (h[idx] - m) * sc + beta[ch];
    if (add) v += add[idx];
    out[idx] = v;
}

// ---------------- flash-style attention ----------------
// grid (Hh, Nn/64, Bg), 256 threads. Block handles 64 Q-rows of one (b,h).
// Heads innermost in grid.x so blocks sharing an sph slice run adjacently (L2).
__global__ __launch_bounds__(256) void attn_k(
    const float* __restrict__ q, const float* __restrict__ k,
    const float* __restrict__ v, const float* __restrict__ sph,
    float* __restrict__ o)
{
    const int h  = blockIdx.x;
    const int n0 = blockIdx.y * 64;
    const int b  = blockIdx.z;
    const int t  = threadIdx.x;
    const int tg = t >> 4;          // 0..15 : row group, r0 = tg*4
    const int tl = t & 15;          // 0..15 : col lane
    const int r0 = tg * 4;
    const int c0 = tl * 4;          // score cols
    const int cv = tl * 2;          // O / PV cols (0..31)

    __shared__ float Qs[64][33];
    __shared__ float Ks[64][33];
    __shared__ float Vs[64][33];
    __shared__ float Ss[64][65];

    const float scale = 0.17677669529663687f;  // 1/sqrt(32)

    // load Q tile [64 rows x 32 cols]
    #pragma unroll
    for (int i = 0; i < 8; ++i) {
        int lin = t + i * 256;          // 0..2047
        int r = lin >> 5, c = lin & 31;
        Qs[r][c] = q[((size_t)(b * Nn + n0 + r)) * Cc + h * DK + c];
    }

    float m_run[4], l_run[4];
    float oacc[4][2] = {};
    #pragma unroll
    for (int i = 0; i < 4; ++i) { m_run[i] = -1e30f; l_run[i] = 0.f; }

    for (int m0 = 0; m0 < Nn; m0 += 64) {
        __syncthreads();   // protect Ks/Vs reuse from previous iteration
        // load K,V tiles
        #pragma unroll
        for (int i = 0; i < 8; ++i) {
            int lin = t + i * 256;
            int r = lin >> 5, c = lin & 31;
            Ks[r][c] = k[((size_t)(b * Nn + m0 + r)) * Cc + h * DK + c];
            Vs[r][c] = v[((size_t)(b * Nn + m0 + r)) * Cc + h * DK + c];
        }
        __syncthreads();

        // scores: 4x4 per thread
        float s[4][4] = {};
        #pragma unroll
        for (int kk = 0; kk < DK; ++kk) {
            float a[4], bb[4];
            #pragma unroll
            for (int i = 0; i < 4; ++i) a[i]  = Qs[r0 + i][kk];
            #pragma unroll
            for (int j = 0; j < 4; ++j) bb[j] = Ks[c0 + j][kk];
            #pragma unroll
            for (int i = 0; i < 4; ++i)
                #pragma unroll
                for (int j = 0; j < 4; ++j)
                    s[i][j] += a[i] * bb[j];
        }
        // sph modulation
        #pragma unroll
        for (int i = 0; i < 4; ++i) {
            const float* sp = &sph[((size_t)(b * Nn + n0 + r0 + i)) * Nn + m0 + c0];
            #pragma unroll
            for (int j = 0; j < 4; ++j)
                s[i][j] *= scale * sp[j];
        }

        // online softmax: row max over 64 cols (16 lanes x 4 each)
        float tmax[4];
        #pragma unroll
        for (int i = 0; i < 4; ++i)
            tmax[i] = fmaxf(fmaxf(s[i][0], s[i][1]), fmaxf(s[i][2], s[i][3]));
        #pragma unroll
        for (int off = 1; off < 16; off <<= 1)
            #pragma unroll
            for (int i = 0; i < 4; ++i)
                tmax[i] = fmaxf(tmax[i], __shfl_xor(tmax[i], off));

        float tsum[4];
        #pragma unroll
        for (int i = 0; i < 4; ++i) {
            float nm = fmaxf(m_run[i], tmax[i]);
            float alpha = __expf(m_run[i] - nm);
            m_run[i] = nm;
            float rs = 0.f;
            #pragma unroll
            for (int j = 0; j < 4; ++j) {
                float p = __expf(s[i][j] - nm);
                Ss[r0 + i][c0 + j] = p;
                rs += p;
            }
            tsum[i] = rs;
            l_run[i] = l_run[i] * alpha;
            oacc[i][0] *= alpha;
            oacc[i][1] *= alpha;
        }
        #pragma unroll
        for (int off = 1; off < 16; off <<= 1)
            #pragma unroll
            for (int i = 0; i < 4; ++i)
                tsum[i] += __shfl_xor(tsum[i], off);
        #pragma unroll
        for (int i = 0; i < 4; ++i) l_run[i] += tsum[i];

        __syncthreads();   // Ss complete

        // PV: oacc[i][j] += sum_m P[r0+i][m] * V[m][cv+j]
        #pragma unroll 4
        for (int mm = 0; mm < 64; ++mm) {
            float v0 = Vs[mm][cv], v1 = Vs[mm][cv + 1];
            #pragma unroll
            for (int i = 0; i < 4; ++i) {
                float p = Ss[r0 + i][mm];
                oacc[i][0] += p * v0;
                oacc[i][1] += p * v1;
            }
        }
    }

    // write O
    #pragma unroll
    for (int i = 0; i < 4; ++i) {
        float inv = 1.f / l_run[i];
        size_t base = ((size_t)(b * Nn + n0 + r0 + i)) * Cc + h * DK + cv;
        o[base]     = oacc[i][0] * inv;
        o[base + 1] = oacc[i][1] * inv;
    }
}

// ---------------- launch ----------------
extern "C" void kernel_launch(void* const* d_in, const int* in_sizes, int n_in,
                              void* d_out, int out_size, void* d_ws, size_t ws_size,
                              hipStream_t stream)
{
    const float* x   = (const float*)d_in[0];
    const int*   ei  = (const int*)  d_in[1];
    const float* sph = (const float*)d_in[2];
    const float* Wr  = (const float*)d_in[3];
    const float* Wn  = (const float*)d_in[4];
    const float* Wq  = (const float*)d_in[5];
    const float* bq  = (const float*)d_in[6];
    const float* Wk  = (const float*)d_in[7];
    const float* bk  = (const float*)d_in[8];
    const float* Wv  = (const float*)d_in[9];
    const float* bv  = (const float*)d_in[10];
    const float* Wo  = (const float*)d_in[11];
    const float* bo  = (const float*)d_in[12];
    const float* W1  = (const float*)d_in[13];
    const float* b1  = (const float*)d_in[14];
    const float* W2  = (const float*)d_in[15];
    const float* b2  = (const float*)d_in[16];
    const float* g1  = (const float*)d_in[17];
    const float* be1 = (const float*)d_in[18];
    const float* g2  = (const float*)d_in[19];
    const float* be2 = (const float*)d_in[20];
    const float* g3  = (const float*)d_in[21];
    const float* be3 = (const float*)d_in[22];
    float* out = (float*)d_out;

    const size_t SL = (size_t)BNn * Cc;  // 2M floats
    float* ws = (float*)d_ws;
    float* s0 = ws;
    float* s1 = ws + SL;
    float* s2 = ws + 2 * SL;
    float* s3 = ws + 3 * SL;
    float* s4 = ws + 4 * SL;
    float* hid = ws + 5 * SL;            // 4M floats (8192 x 512)
    float* stats = ws + 7 * SL;          // 512 floats (sum | sumsq)

    dim3 gB(4, 128);
    dim3 gB512(8, 128);

    // 1) xWn = x @ Wn
    gemm_k<<<gB, 256, 0, stream>>>(x, Wn, nullptr, nullptr, nullptr, s0, BNn, Cc, Cc, 0);
    // 2) agg = segment_sum(xWn[src], dst)
    hipMemsetAsync(s1, 0, SL * sizeof(float), stream);
    scatter_k<<<Ee, 256, 0, stream>>>(s0, ei, s1);
    // 3) h1pre = x @ Wr + agg + x
    gemm_k<<<gB, 256, 0, stream>>>(x, Wr, nullptr, s1, x, s2, BNn, Cc, Cc, 0);
    // 4) h1 = BN1(h1pre)  -> s3
    hipMemsetAsync(stats, 0, 512 * sizeof(float), stream);
    bn_stats_k<<<256, 256, 0, stream>>>(s2, stats, stats + 256);
    bn_apply_k<<<BNn, 256, 0, stream>>>(s2, stats, stats + 256, g1, be1, nullptr, s3);
    // 5) q,k,v projections
    gemm_k<<<gB, 256, 0, stream>>>(x, Wq, bq, nullptr, nullptr, s0, BNn, Cc, Cc, 0);
    gemm_k<<<gB, 256, 0, stream>>>(x, Wk, bk, nullptr, nullptr, s1, BNn, Cc, Cc, 0);
    gemm_k<<<gB, 256, 0, stream>>>(x, Wv, bv, nullptr, nullptr, s2, BNn, Cc, Cc, 0);
    // 6) attention -> s4  (o in [b,n,h,dk] = [BNn, Cc] layout)
    attn_k<<<dim3(Hh, Nn / 64, Bg), 256, 0, stream>>>(s0, s1, s2, sph, s4);
    // 7) h2pre = o @ Wo + bo + x -> s0
    gemm_k<<<gB, 256, 0, stream>>>(s4, Wo, bo, x, nullptr, s0, BNn, Cc, Cc, 0);
    // 8) outsum = BN2(h2pre) + h1 -> s1
    hipMemsetAsync(stats, 0, 512 * sizeof(float), stream);
    bn_stats_k<<<256, 256, 0, stream>>>(s0, stats, stats + 256);
    bn_apply_k<<<BNn, 256, 0, stream>>>(s0, stats, stats + 256, g2, be2, s3, s1);
    // 9) hidden = relu(outsum @ W1 + b1)
    gemm_k<<<gB512, 256, 0, stream>>>(s1, W1, b1, nullptr, nullptr, hid, BNn, Cc, 2 * Cc, 1);
    // 10) out2 = hidden @ W2 + b2 + outsum -> s2
    gemm_k<<<gB, 256, 0, stream>>>(hid, W2, b2, s1, nullptr, s2, BNn, 2 * Cc, Cc, 0);
    // 11) d_out = BN3(out2)
    hipMemsetAsync(stats, 0, 512 * sizeof(float), stream);
    bn_stats_k<<<256, 256, 0, stream>>>(s2, stats, stats + 256);
    bn_apply_k<<<BNn, 256, 0, stream>>>(s2, stats, stats + 256, g3, be3, nullptr, out);
}

// Round 3
// 484.790 us; speedup vs baseline: 4.1168x; 1.7990x over previous
//
#include <hip/hip_runtime.h>
#include <hip/hip_bf16.h>

// ---------------- problem constants ----------------
constexpr int Bg  = 8;       // graphs
constexpr int Nn  = 1024;    // nodes per graph
constexpr int Cc  = 256;     // channels
constexpr int Hh  = 8;       // heads
constexpr int DKh = 32;      // head dim
constexpr int Ee  = 131072;  // edges
constexpr int BNn = Bg * Nn; // 8192 total nodes
#define EPSV 1e-5f

typedef __attribute__((ext_vector_type(8))) short bf16x8;
typedef __attribute__((ext_vector_type(4))) float f32x4;

static __device__ __forceinline__ unsigned short f2b(float v) {
    __hip_bfloat16 h = __float2bfloat16(v);
    return __builtin_bit_cast(unsigned short, h);
}
static __device__ __forceinline__ bf16x8 ldb8(const unsigned short* p) {
    return *(const bf16x8*)p;
}

// ---------------- fp32 -> bf16 convert (x) ----------------
__global__ __launch_bounds__(256) void xconv_k(
    const float* __restrict__ x, unsigned short* __restrict__ xb)
{
    int i = (blockIdx.x * 256 + threadIdx.x) * 4;
    float4 v = *(const float4*)(x + i);
    xb[i]     = f2b(v.x);
    xb[i + 1] = f2b(v.y);
    xb[i + 2] = f2b(v.z);
    xb[i + 3] = f2b(v.w);
}

// ---------------- weight transpose+convert: WT[n][k] = bf16(W[k][n]) ----------------
// 6x 256x256, 1x 256x512 (W1), 1x 512x256 (W2). total 655360 elements.
__global__ __launch_bounds__(256) void wconv_k(
    const float* __restrict__ Wr, const float* __restrict__ Wn,
    const float* __restrict__ Wq, const float* __restrict__ Wk,
    const float* __restrict__ Wv, const float* __restrict__ Wo,
    const float* __restrict__ W1, const float* __restrict__ W2,
    unsigned short* __restrict__ WrT, unsigned short* __restrict__ WnT,
    unsigned short* __restrict__ WqT, unsigned short* __restrict__ WkT,
    unsigned short* __restrict__ WvT, unsigned short* __restrict__ WoT,
    unsigned short* __restrict__ W1T, unsigned short* __restrict__ W2T)
{
    int idx = blockIdx.x * 256 + threadIdx.x;
    if (idx < 393216) {
        int wsel = idx >> 16, l = idx & 65535;
        int n = l >> 8, kk = l & 255;
        const float* S = wsel == 0 ? Wr : wsel == 1 ? Wn : wsel == 2 ? Wq
                       : wsel == 3 ? Wk : wsel == 4 ? Wv : Wo;
        unsigned short* D = wsel == 0 ? WrT : wsel == 1 ? WnT : wsel == 2 ? WqT
                          : wsel == 3 ? WkT : wsel == 4 ? WvT : WoT;
        D[n * 256 + kk] = f2b(S[kk * 256 + n]);
    } else if (idx < 524288) {
        int l = idx - 393216;             // W1: [256][512] -> W1T [512][256]
        int n = l >> 8, kk = l & 255;
        W1T[l] = f2b(W1[kk * 512 + n]);
    } else {
        int l = idx - 524288;             // W2: [512][256] -> W2T [256][512]
        int n = l >> 9, kk = l & 511;
        W2T[l] = f2b(W2[kk * 256 + n]);
    }
}

// ---------------- MFMA GEMM ----------------
// out = maybe_relu( A_bf16[M,K] @ (WT_bf16[N,K])^T + bias? + add1? + add2? )
// 64x64 tile, 256 threads = 4 waves (2x2 of 32x32), fragments direct from global.
// outf (fp32) and/or outb (bf16) outputs; vtrans writes outb as [b,h,d,n].
__global__ __launch_bounds__(256) void gemm_mfma_k(
    const unsigned short* __restrict__ A, const unsigned short* __restrict__ WT,
    const float* __restrict__ bias, const float* __restrict__ add1,
    const float* __restrict__ add2, float* __restrict__ outf,
    unsigned short* __restrict__ outb,
    int M, int K, int N, int relu, int vtrans)
{
    const int t = threadIdx.x;
    const int wave = t >> 6, lane = t & 63;
    const int tl = lane & 15, g = lane >> 4;
    const int wr = wave >> 1, wc = wave & 1;
    const int m0 = blockIdx.y * 64, n0 = blockIdx.x * 64;

    f32x4 acc[2][2] = {};

    const unsigned short* a0 = A  + (size_t)(m0 + wr * 32 + tl) * K + g * 8;
    const unsigned short* a1 = a0 + (size_t)16 * K;
    const unsigned short* b0 = WT + (size_t)(n0 + wc * 32 + tl) * K + g * 8;
    const unsigned short* b1 = b0 + (size_t)16 * K;

    for (int k0 = 0; k0 < K; k0 += 32) {
        bf16x8 af0 = ldb8(a0 + k0), af1 = ldb8(a1 + k0);
        bf16x8 bf0 = ldb8(b0 + k0), bf1 = ldb8(b1 + k0);
        acc[0][0] = __builtin_amdgcn_mfma_f32_16x16x32_bf16(af0, bf0, acc[0][0], 0, 0, 0);
        acc[0][1] = __builtin_amdgcn_mfma_f32_16x16x32_bf16(af0, bf1, acc[0][1], 0, 0, 0);
        acc[1][0] = __builtin_amdgcn_mfma_f32_16x16x32_bf16(af1, bf0, acc[1][0], 0, 0, 0);
        acc[1][1] = __builtin_amdgcn_mfma_f32_16x16x32_bf16(af1, bf1, acc[1][1], 0, 0, 0);
    }

    #pragma unroll
    for (int r16 = 0; r16 < 2; ++r16)
        #pragma unroll
        for (int c16 = 0; c16 < 2; ++c16)
            #pragma unroll
            for (int reg = 0; reg < 4; ++reg) {
                int row = m0 + wr * 32 + r16 * 16 + g * 4 + reg;
                int col = n0 + wc * 32 + c16 * 16 + tl;
                float v = acc[r16][c16][reg];
                if (bias) v += bias[col];
                size_t idx = (size_t)row * N + col;
                if (add1) v += add1[idx];
                if (add2) v += add2[idx];
                if (relu) v = fmaxf(v, 0.f);
                if (outf) outf[idx] = v;
                if (outb) {
                    if (vtrans) {
                        int bg = row >> 10, n = row & 1023;
                        int hh = col >> 5,  d = col & 31;
                        outb[((size_t)((bg * Hh + hh) * DKh + d)) * Nn + n] = f2b(v);
                    } else {
                        outb[idx] = f2b(v);
                    }
                }
            }
}

// ---------------- edge scatter: agg[dst] += xWn[src] ----------------
__global__ __launch_bounds__(256) void scatter_k(
    const float* __restrict__ xWn, const int* __restrict__ ei,
    float* __restrict__ agg)
{
    int e = blockIdx.x;
    int c = threadIdx.x;
    int s = ei[e];
    int d = ei[Ee + e];
    atomicAdd(&agg[(size_t)d * Cc + c], xWn[(size_t)s * Cc + c]);
}

// ---------------- BN stats: per-channel sum & sumsq ----------------
__global__ __launch_bounds__(256) void bn_stats_k(
    const float* __restrict__ h, float* __restrict__ gsum, float* __restrict__ gsq)
{
    int ch = threadIdx.x;
    int r0 = blockIdx.x * 32;
    float s = 0.f, s2 = 0.f;
    for (int r = r0; r < r0 + 32; ++r) {
        float v = h[(size_t)r * Cc + ch];
        s += v; s2 += v * v;
    }
    atomicAdd(&gsum[ch], s);
    atomicAdd(&gsq[ch], s2);
}

// ---------------- BN apply ----------------
__global__ __launch_bounds__(256) void bn_apply_k(
    const float* __restrict__ h, const float* __restrict__ gsum,
    const float* __restrict__ gsq, const float* __restrict__ gamma,
    const float* __restrict__ beta, const float* __restrict__ add,
    float* __restrict__ outf, unsigned short* __restrict__ outb)
{
    size_t idx = (size_t)blockIdx.x * 256 + threadIdx.x;
    int ch = (int)(idx & (Cc - 1));
    float m   = gsum[ch] * (1.f / BNn);
    float var = gsq[ch] * (1.f / BNn) - m * m;
    float sc  = rsqrtf(var + EPSV) * gamma[ch];
    float v = (h[idx] - m) * sc + beta[ch];
    if (add) v += add[idx];
    if (outf) outf[idx] = v;
    if (outb) outb[idx] = f2b(v);
}

// ---------------- MFMA flash attention ----------------
// grid (Hh, Nn/64, Bg), 256 threads = 4 waves; wave w owns Q rows w*16..w*16+15.
// q,k: bf16 [BNn, Cc]; vT: bf16 [b,h,d,n]; o: bf16 [BNn, Cc].
__global__ __launch_bounds__(256) void attn_k(
    const unsigned short* __restrict__ q, const unsigned short* __restrict__ k,
    const unsigned short* __restrict__ vT, const float* __restrict__ sph,
    unsigned short* __restrict__ o)
{
    const int h  = blockIdx.x;
    const int n0 = blockIdx.y * 64;
    const int b  = blockIdx.z;
    const int t  = threadIdx.x;
    const int w  = t >> 6, lane = t & 63;
    const int tl = lane & 15, g = lane >> 4;

    __shared__ unsigned short Ss[64][72];   // P tile, bf16; stride 72 breaks pow2 banks

    const float scale = 0.17677669529663687f;  // 1/sqrt(32)

    // Q A-fragment: row = w*16 + tl, k = g*8 + j  (16B contiguous)
    bf16x8 qa = ldb8(q + ((size_t)(b * Nn + n0 + w * 16 + tl)) * Cc + h * DKh + g * 8);

    float m_run[4], l_run[4];
    f32x4 oacc[2] = {};
    #pragma unroll
    for (int r = 0; r < 4; ++r) { m_run[r] = -1e30f; l_run[r] = 0.f; }

    // sph row pointers for this lane's 4 rows (C-layout rows g*4+r)
    const float* sprow[4];
    #pragma unroll
    for (int r = 0; r < 4; ++r)
        sprow[r] = sph + ((size_t)b * Nn + n0 + w * 16 + g * 4 + r) * Nn;

    for (int m0 = 0; m0 < Nn; m0 += 64) {
        // scores: 4 col-groups of 16; K=32 in one MFMA
        f32x4 s[4];
        #pragma unroll
        for (int cg = 0; cg < 4; ++cg) {
            bf16x8 kb = ldb8(k + ((size_t)(b * Nn + m0 + cg * 16 + tl)) * Cc + h * DKh + g * 8);
            f32x4 z = {0.f, 0.f, 0.f, 0.f};
            s[cg] = __builtin_amdgcn_mfma_f32_16x16x32_bf16(qa, kb, z, 0, 0, 0);
        }

        // sph modulation
        float sv[4][4];  // [cg][reg]
        #pragma unroll
        for (int cg = 0; cg < 4; ++cg)
            #pragma unroll
            for (int r = 0; r < 4; ++r)
                sv[cg][r] = s[cg][r] * scale * sprow[r][m0 + cg * 16 + tl];

        // row max across 64 cols: local over cg, then 16-lane butterfly
        float tmax[4];
        #pragma unroll
        for (int r = 0; r < 4; ++r)
            tmax[r] = fmaxf(fmaxf(sv[0][r], sv[1][r]), fmaxf(sv[2][r], sv[3][r]));
        #pragma unroll
        for (int off = 1; off < 16; off <<= 1)
            #pragma unroll
            for (int r = 0; r < 4; ++r)
                tmax[r] = fmaxf(tmax[r], __shfl_xor(tmax[r], off));

        float alpha[4], tsum[4];
        #pragma unroll
        for (int r = 0; r < 4; ++r) {
            float nm = fmaxf(m_run[r], tmax[r]);
            alpha[r] = __expf(m_run[r] - nm);
            m_run[r] = nm;
            float rs = 0.f;
            #pragma unroll
            for (int cg = 0; cg < 4; ++cg) {
                float p = __expf(sv[cg][r] - nm);
                Ss[w * 16 + g * 4 + r][cg * 16 + tl] = f2b(p);
                rs += p;
            }
            tsum[r] = rs;
        }
        #pragma unroll
        for (int off = 1; off < 16; off <<= 1)
            #pragma unroll
            for (int r = 0; r < 4; ++r)
                tsum[r] += __shfl_xor(tsum[r], off);
        #pragma unroll
        for (int r = 0; r < 4; ++r)
            l_run[r] = l_run[r] * alpha[r] + tsum[r];

        // rescale O accumulators
        #pragma unroll
        for (int cg2 = 0; cg2 < 2; ++cg2)
            #pragma unroll
            for (int r = 0; r < 4; ++r)
                oacc[cg2][r] *= alpha[r];

        __syncthreads();  // P visible (wave-private rows, but keep ordering safe)

        // PV: O[16x32] += P[16x64] @ V[64x32]; A from LDS, B from vT (contiguous)
        #pragma unroll
        for (int ks = 0; ks < 2; ++ks) {
            bf16x8 pa = ldb8(&Ss[w * 16 + tl][ks * 32 + g * 8]);
            #pragma unroll
            for (int cg2 = 0; cg2 < 2; ++cg2) {
                bf16x8 vb = ldb8(vT + ((size_t)((b * Hh + h) * DKh + cg2 * 16 + tl)) * Nn
                                    + m0 + ks * 32 + g * 8);
                oacc[cg2] = __builtin_amdgcn_mfma_f32_16x16x32_bf16(pa, vb, oacc[cg2], 0, 0, 0);
            }
        }
        __syncthreads();  // protect Ss reuse next iteration
    }

    // write O (bf16, feeds Wo GEMM)
    #pragma unroll
    for (int cg2 = 0; cg2 < 2; ++cg2)
        #pragma unroll
        for (int r = 0; r < 4; ++r) {
            float inv = 1.f / l_run[r];
            o[((size_t)(b * Nn + n0 + w * 16 + g * 4 + r)) * Cc + h * DKh + cg2 * 16 + tl]
                = f2b(oacc[cg2][r] * inv);
        }
}

// ---------------- launch ----------------
extern "C" void kernel_launch(void* const* d_in, const int* in_sizes, int n_in,
                              void* d_out, int out_size, void* d_ws, size_t ws_size,
                              hipStream_t stream)
{
    const float* x   = (const float*)d_in[0];
    const int*   ei  = (const int*)  d_in[1];
    const float* sph = (const float*)d_in[2];
    const float* Wr  = (const float*)d_in[3];
    const float* Wn  = (const float*)d_in[4];
    const float* Wq  = (const float*)d_in[5];
    const float* bq  = (const float*)d_in[6];
    const float* Wk  = (const float*)d_in[7];
    const float* bk  = (const float*)d_in[8];
    const float* Wv  = (const float*)d_in[9];
    const float* bv  = (const float*)d_in[10];
    const float* Wo  = (const float*)d_in[11];
    const float* bo  = (const float*)d_in[12];
    const float* W1  = (const float*)d_in[13];
    const float* b1  = (const float*)d_in[14];
    const float* W2  = (const float*)d_in[15];
    const float* b2  = (const float*)d_in[16];
    const float* g1  = (const float*)d_in[17];
    const float* be1 = (const float*)d_in[18];
    const float* g2  = (const float*)d_in[19];
    const float* be2 = (const float*)d_in[20];
    const float* g3  = (const float*)d_in[21];
    const float* be3 = (const float*)d_in[22];
    float* out = (float*)d_out;

    const size_t SL = (size_t)BNn * Cc;  // 2M elements
    float* ws = (float*)d_ws;
    float* s0 = ws;                 // xWn -> h2pre
    float* s1 = s0 + SL;            // agg -> outsum
    float* s2 = s1 + SL;            // h1pre -> out2
    float* s3 = s2 + SL;            // h1
    float* stats = s3 + SL;         // 512 floats

    unsigned short* bb  = (unsigned short*)(stats + 512);
    unsigned short* xb  = bb;            // 2M shorts; reused as ob after QKV
    unsigned short* qb  = xb + SL;       // reused as outsum_b after attn
    unsigned short* kb  = qb + SL;       // kb+vT region reused as hid_b (4M)
    unsigned short* vTb = kb + SL;
    unsigned short* ob  = xb;
    unsigned short* osb = qb;
    unsigned short* hid = kb;
    unsigned short* WnT = vTb + SL;
    unsigned short* WrT = WnT + 65536;
    unsigned short* WqT = WrT + 65536;
    unsigned short* WkT = WqT + 65536;
    unsigned short* WvT = WkT + 65536;
    unsigned short* WoT = WvT + 65536;
    unsigned short* W1T = WoT + 65536;
    unsigned short* W2T = W1T + 131072;

    dim3 g256(4, 128);     // N=256 GEMMs
    dim3 g512(8, 128);     // N=512 GEMM (MLP1)

    // 0) converts
    xconv_k<<<2048, 256, 0, stream>>>(x, xb);
    wconv_k<<<2560, 256, 0, stream>>>(Wr, Wn, Wq, Wk, Wv, Wo, W1, W2,
                                      WrT, WnT, WqT, WkT, WvT, WoT, W1T, W2T);

    // 1) xWn = x @ Wn (fp32 out, feeds scatter)
    gemm_mfma_k<<<g256, 256, 0, stream>>>(xb, WnT, nullptr, nullptr, nullptr,
                                          s0, nullptr, BNn, Cc, Cc, 0, 0);
    // 2) agg = segment_sum(xWn[src], dst)
    hipMemsetAsync(s1, 0, SL * sizeof(float), stream);
    scatter_k<<<Ee, 256, 0, stream>>>(s0, ei, s1);
    // 3) h1pre = x @ Wr + agg + x
    gemm_mfma_k<<<g256, 256, 0, stream>>>(xb, WrT, nullptr, s1, x,
                                          s2, nullptr, BNn, Cc, Cc, 0, 0);
    // 4) h1 = BN1(h1pre) -> s3
    hipMemsetAsync(stats, 0, 512 * sizeof(float), stream);
    bn_stats_k<<<256, 256, 0, stream>>>(s2, stats, stats + 256);
    bn_apply_k<<<BNn, 256, 0, stream>>>(s2, stats, stats + 256, g1, be1, nullptr, s3, nullptr);
    // 5) q,k,v projections (bf16 out; v transposed [b,h,d,n])
    gemm_mfma_k<<<g256, 256, 0, stream>>>(xb, WqT, bq, nullptr, nullptr,
                                          nullptr, qb, BNn, Cc, Cc, 0, 0);
    gemm_mfma_k<<<g256, 256, 0, stream>>>(xb, WkT, bk, nullptr, nullptr,
                                          nullptr, kb, BNn, Cc, Cc, 0, 0);
    gemm_mfma_k<<<g256, 256, 0, stream>>>(xb, WvT, bv, nullptr, nullptr,
                                          nullptr, vTb, BNn, Cc, Cc, 0, 1);
    // 6) attention -> ob (bf16)
    attn_k<<<dim3(Hh, Nn / 64, Bg), 256, 0, stream>>>(qb, kb, vTb, sph, ob);
    // 7) h2pre = o @ Wo + bo + x -> s0
    gemm_mfma_k<<<g256, 256, 0, stream>>>(ob, WoT, bo, x, nullptr,
                                          s0, nullptr, BNn, Cc, Cc, 0, 0);
    // 8) outsum = BN2(h2pre) + h1 -> s1 (fp32) + osb (bf16)
    hipMemsetAsync(stats, 0, 512 * sizeof(float), stream);
    bn_stats_k<<<256, 256, 0, stream>>>(s0, stats, stats + 256);
    bn_apply_k<<<BNn, 256, 0, stream>>>(s0, stats, stats + 256, g2, be2, s3, s1, osb);
    // 9) hidden = relu(outsum @ W1 + b1) -> hid (bf16)
    gemm_mfma_k<<<g512, 256, 0, stream>>>(osb, W1T, b1, nullptr, nullptr,
                                          nullptr, hid, BNn, Cc, 2 * Cc, 1, 0);
    // 10) out2 = hidden @ W2 + b2 + outsum -> s2
    gemm_mfma_k<<<g256, 256, 0, stream>>>(hid, W2T, b2, s1, nullptr,
                                          s2, nullptr, BNn, 2 * Cc, Cc, 0, 0);
    // 11) d_out = BN3(out2)
    hipMemsetAsync(stats, 0, 512 * sizeof(float), stream);
    bn_stats_k<<<256, 256, 0, stream>>>(s2, stats, stats + 256);
    bn_apply_k<<<BNn, 256, 0, stream>>>(s2, stats, stats + 256, g3, be3, nullptr, out, nullptr);
}

// Round 4
// 420.856 us; speedup vs baseline: 4.7421x; 1.1519x over previous
//
#include <hip/hip_runtime.h>
#include <hip/hip_bf16.h>

// ---------------- problem constants ----------------
constexpr int Bg  = 8;       // graphs
constexpr int Nn  = 1024;    // nodes per graph
constexpr int Cc  = 256;     // channels
constexpr int Hh  = 8;       // heads
constexpr int DKh = 32;      // head dim
constexpr int Ee  = 131072;  // edges
constexpr int BNn = Bg * Nn; // 8192 total nodes
#define EPSV 1e-5f

typedef __attribute__((ext_vector_type(8))) short bf16x8;
typedef __attribute__((ext_vector_type(4))) float f32x4;

static __device__ __forceinline__ unsigned short f2b(float v) {
    __hip_bfloat16 h = __float2bfloat16(v);
    return __builtin_bit_cast(unsigned short, h);
}
static __device__ __forceinline__ bf16x8 ldb8(const unsigned short* p) {
    return *(const bf16x8*)p;
}

// ---------------- x -> bf16 into xcat[n][0:256] (row stride 512) ----------------
__global__ __launch_bounds__(256) void xconv_k(
    const float* __restrict__ x, unsigned short* __restrict__ xcat)
{
    int i = (blockIdx.x * 256 + threadIdx.x) * 4;
    float4 v = *(const float4*)(x + i);
    int r = i >> 8, c = i & 255;
    unsigned short* d = xcat + (size_t)r * 512 + c;
    d[0] = f2b(v.x); d[1] = f2b(v.y); d[2] = f2b(v.z); d[3] = f2b(v.w);
}

// ---------------- weight transpose+convert ----------------
// WcatT[256][512]: k<256 -> Wr^T, k>=256 -> Wn^T. Then WqT/WkT/WvT/WoT, W1T, W2T.
__global__ __launch_bounds__(256) void wconv_k(
    const float* __restrict__ Wr, const float* __restrict__ Wn,
    const float* __restrict__ Wq, const float* __restrict__ Wk,
    const float* __restrict__ Wv, const float* __restrict__ Wo,
    const float* __restrict__ W1, const float* __restrict__ W2,
    unsigned short* __restrict__ WcatT,
    unsigned short* __restrict__ WqT, unsigned short* __restrict__ WkT,
    unsigned short* __restrict__ WvT, unsigned short* __restrict__ WoT,
    unsigned short* __restrict__ W1T, unsigned short* __restrict__ W2T)
{
    int idx = blockIdx.x * 256 + threadIdx.x;
    if (idx < 131072) {                      // WcatT
        int n = idx >> 9, k = idx & 511;
        float v = (k < 256) ? Wr[k * 256 + n] : Wn[(k - 256) * 256 + n];
        WcatT[(size_t)n * 512 + k] = f2b(v);
    } else if (idx < 393216) {               // q,k,v,o
        int l = idx - 131072;
        int wsel = l >> 16; l &= 65535;
        int n = l >> 8, kk = l & 255;
        const float* S = wsel == 0 ? Wq : wsel == 1 ? Wk : wsel == 2 ? Wv : Wo;
        unsigned short* D = wsel == 0 ? WqT : wsel == 1 ? WkT : wsel == 2 ? WvT : WoT;
        D[n * 256 + kk] = f2b(S[kk * 256 + n]);
    } else if (idx < 524288) {               // W1 [256][512] -> W1T [512][256]
        int l = idx - 393216;
        int n = l >> 8, kk = l & 255;
        W1T[l] = f2b(W1[kk * 512 + n]);
    } else {                                 // W2 [512][256] -> W2T [256][512]
        int l = idx - 524288;
        int n = l >> 9, kk = l & 511;
        W2T[l] = f2b(W2[kk * 256 + n]);
    }
}

// ---------------- CSR build ----------------
__global__ __launch_bounds__(256) void hist_k(
    const int* __restrict__ ei, int* __restrict__ deg)
{
    int e = blockIdx.x * 256 + threadIdx.x;
    atomicAdd(&deg[ei[Ee + e]], 1);
}

__global__ __launch_bounds__(256) void scan_k(
    const int* __restrict__ deg, int* __restrict__ rowst, int* __restrict__ cursor)
{
    __shared__ int partial[256];
    int t = threadIdx.x;
    int local[32];
    int s = 0;
    #pragma unroll
    for (int i = 0; i < 32; ++i) { local[i] = deg[t * 32 + i]; s += local[i]; }
    partial[t] = s;
    __syncthreads();
    for (int off = 1; off < 256; off <<= 1) {
        int v = (t >= off) ? partial[t - off] : 0;
        __syncthreads();
        partial[t] += v;
        __syncthreads();
    }
    int base = partial[t] - s;   // exclusive prefix of this thread's chunk
    #pragma unroll
    for (int i = 0; i < 32; ++i) {
        int idx = t * 32 + i;
        rowst[idx] = base;
        cursor[idx] = base;
        base += local[i];
    }
    if (t == 255) rowst[8192] = base;
}

__global__ __launch_bounds__(256) void place_k(
    const int* __restrict__ ei, int* __restrict__ cursor, int* __restrict__ eidx)
{
    int e = blockIdx.x * 256 + threadIdx.x;
    int s = ei[e], d = ei[Ee + e];
    int pos = atomicAdd(&cursor[d], 1);
    eidx[pos] = s;
}

// ---------------- gather: aggx[n] = sum_{e: dst=n} x[src_e]  (bf16 into xcat hi) ----------------
__global__ __launch_bounds__(256) void gather_k(
    const float* __restrict__ x, const int* __restrict__ rowst,
    const int* __restrict__ eidx, unsigned short* __restrict__ xcat)
{
    int n = blockIdx.x, c = threadIdx.x;
    int b0 = rowst[n], b1 = rowst[n + 1];
    float acc = 0.f;
    for (int i = b0; i < b1; ++i) {
        int s = eidx[i];
        acc += x[(size_t)s * Cc + c];
    }
    xcat[(size_t)n * 512 + 256 + c] = f2b(acc);
}

// ---------------- MFMA GEMM ----------------
// out = maybe_relu( A_bf16[M,K](lda) @ (WT_bf16[N,K])^T + bias? + add1? + add2? )
// 64x64 tile, 256 threads = 4 waves (2x2 of 32x32), fragments direct from global.
__global__ __launch_bounds__(256) void gemm_mfma_k(
    const unsigned short* __restrict__ A, const unsigned short* __restrict__ WT,
    const float* __restrict__ bias, const float* __restrict__ add1,
    const float* __restrict__ add2, float* __restrict__ outf,
    unsigned short* __restrict__ outb,
    int M, int K, int lda, int N, int relu, int vtrans)
{
    const int t = threadIdx.x;
    const int wave = t >> 6, lane = t & 63;
    const int tl = lane & 15, g = lane >> 4;
    const int wr = wave >> 1, wc = wave & 1;
    const int m0 = blockIdx.y * 64, n0 = blockIdx.x * 64;

    f32x4 acc[2][2] = {};

    const unsigned short* a0 = A  + (size_t)(m0 + wr * 32 + tl) * lda + g * 8;
    const unsigned short* a1 = a0 + (size_t)16 * lda;
    const unsigned short* b0 = WT + (size_t)(n0 + wc * 32 + tl) * K + g * 8;
    const unsigned short* b1 = b0 + (size_t)16 * K;

    for (int k0 = 0; k0 < K; k0 += 32) {
        bf16x8 af0 = ldb8(a0 + k0), af1 = ldb8(a1 + k0);
        bf16x8 bf0 = ldb8(b0 + k0), bf1 = ldb8(b1 + k0);
        acc[0][0] = __builtin_amdgcn_mfma_f32_16x16x32_bf16(af0, bf0, acc[0][0], 0, 0, 0);
        acc[0][1] = __builtin_amdgcn_mfma_f32_16x16x32_bf16(af0, bf1, acc[0][1], 0, 0, 0);
        acc[1][0] = __builtin_amdgcn_mfma_f32_16x16x32_bf16(af1, bf0, acc[1][0], 0, 0, 0);
        acc[1][1] = __builtin_amdgcn_mfma_f32_16x16x32_bf16(af1, bf1, acc[1][1], 0, 0, 0);
    }

    #pragma unroll
    for (int r16 = 0; r16 < 2; ++r16)
        #pragma unroll
        for (int c16 = 0; c16 < 2; ++c16)
            #pragma unroll
            for (int reg = 0; reg < 4; ++reg) {
                int row = m0 + wr * 32 + r16 * 16 + g * 4 + reg;
                int col = n0 + wc * 32 + c16 * 16 + tl;
                float v = acc[r16][c16][reg];
                if (bias) v += bias[col];
                size_t idx = (size_t)row * N + col;
                if (add1) v += add1[idx];
                if (add2) v += add2[idx];
                if (relu) v = fmaxf(v, 0.f);
                if (outf) outf[idx] = v;
                if (outb) {
                    if (vtrans) {
                        int bg = row >> 10, n = row & 1023;
                        int hh = col >> 5,  d = col & 31;
                        outb[((size_t)((bg * Hh + hh) * DKh + d)) * Nn + n] = f2b(v);
                    } else {
                        outb[idx] = f2b(v);
                    }
                }
            }
}

// ---------------- BN stats: per-channel sum & sumsq ----------------
__global__ __launch_bounds__(256) void bn_stats_k(
    const float* __restrict__ h, float* __restrict__ gsum, float* __restrict__ gsq)
{
    int ch = threadIdx.x;
    int r0 = blockIdx.x * 32;
    float s = 0.f, s2 = 0.f;
    for (int r = r0; r < r0 + 32; ++r) {
        float v = h[(size_t)r * Cc + ch];
        s += v; s2 += v * v;
    }
    atomicAdd(&gsum[ch], s);
    atomicAdd(&gsq[ch], s2);
}

// ---------------- BN apply ----------------
__global__ __launch_bounds__(256) void bn_apply_k(
    const float* __restrict__ h, const float* __restrict__ gsum,
    const float* __restrict__ gsq, const float* __restrict__ gamma,
    const float* __restrict__ beta, const float* __restrict__ add,
    float* __restrict__ outf, unsigned short* __restrict__ outb)
{
    size_t idx = (size_t)blockIdx.x * 256 + threadIdx.x;
    int ch = (int)(idx & (Cc - 1));
    float m   = gsum[ch] * (1.f / BNn);
    float var = gsq[ch] * (1.f / BNn) - m * m;
    float sc  = rsqrtf(var + EPSV) * gamma[ch];
    float v = (h[idx] - m) * sc + beta[ch];
    if (add) v += add[idx];
    if (outf) outf[idx] = v;
    if (outb) outb[idx] = f2b(v);
}

// ---------------- MFMA flash attention ----------------
// grid (Hh, Nn/64, Bg), 256 threads = 4 waves; wave w owns Q rows w*16..w*16+15.
__global__ __launch_bounds__(256) void attn_k(
    const unsigned short* __restrict__ q, const unsigned short* __restrict__ k,
    const unsigned short* __restrict__ vT, const float* __restrict__ sph,
    unsigned short* __restrict__ o)
{
    const int h  = blockIdx.x;
    const int n0 = blockIdx.y * 64;
    const int b  = blockIdx.z;
    const int t  = threadIdx.x;
    const int w  = t >> 6, lane = t & 63;
    const int tl = lane & 15, g = lane >> 4;

    __shared__ unsigned short Ss[64][72];

    const float scale = 0.17677669529663687f;  // 1/sqrt(32)

    bf16x8 qa = ldb8(q + ((size_t)(b * Nn + n0 + w * 16 + tl)) * Cc + h * DKh + g * 8);

    float m_run[4], l_run[4];
    f32x4 oacc[2] = {};
    #pragma unroll
    for (int r = 0; r < 4; ++r) { m_run[r] = -1e30f; l_run[r] = 0.f; }

    const float* sprow[4];
    #pragma unroll
    for (int r = 0; r < 4; ++r)
        sprow[r] = sph + ((size_t)b * Nn + n0 + w * 16 + g * 4 + r) * Nn;

    for (int m0 = 0; m0 < Nn; m0 += 64) {
        f32x4 s[4];
        #pragma unroll
        for (int cg = 0; cg < 4; ++cg) {
            bf16x8 kb = ldb8(k + ((size_t)(b * Nn + m0 + cg * 16 + tl)) * Cc + h * DKh + g * 8);
            f32x4 z = {0.f, 0.f, 0.f, 0.f};
            s[cg] = __builtin_amdgcn_mfma_f32_16x16x32_bf16(qa, kb, z, 0, 0, 0);
        }

        float sv[4][4];
        #pragma unroll
        for (int cg = 0; cg < 4; ++cg)
            #pragma unroll
            for (int r = 0; r < 4; ++r)
                sv[cg][r] = s[cg][r] * scale * sprow[r][m0 + cg * 16 + tl];

        float tmax[4];
        #pragma unroll
        for (int r = 0; r < 4; ++r)
            tmax[r] = fmaxf(fmaxf(sv[0][r], sv[1][r]), fmaxf(sv[2][r], sv[3][r]));
        #pragma unroll
        for (int off = 1; off < 16; off <<= 1)
            #pragma unroll
            for (int r = 0; r < 4; ++r)
                tmax[r] = fmaxf(tmax[r], __shfl_xor(tmax[r], off));

        float alpha[4], tsum[4];
        #pragma unroll
        for (int r = 0; r < 4; ++r) {
            float nm = fmaxf(m_run[r], tmax[r]);
            alpha[r] = __expf(m_run[r] - nm);
            m_run[r] = nm;
            float rs = 0.f;
            #pragma unroll
            for (int cg = 0; cg < 4; ++cg) {
                float p = __expf(sv[cg][r] - nm);
                Ss[w * 16 + g * 4 + r][cg * 16 + tl] = f2b(p);
                rs += p;
            }
            tsum[r] = rs;
        }
        #pragma unroll
        for (int off = 1; off < 16; off <<= 1)
            #pragma unroll
            for (int r = 0; r < 4; ++r)
                tsum[r] += __shfl_xor(tsum[r], off);
        #pragma unroll
        for (int r = 0; r < 4; ++r)
            l_run[r] = l_run[r] * alpha[r] + tsum[r];

        #pragma unroll
        for (int cg2 = 0; cg2 < 2; ++cg2)
            #pragma unroll
            for (int r = 0; r < 4; ++r)
                oacc[cg2][r] *= alpha[r];

        __syncthreads();

        #pragma unroll
        for (int ks = 0; ks < 2; ++ks) {
            bf16x8 pa = ldb8(&Ss[w * 16 + tl][ks * 32 + g * 8]);
            #pragma unroll
            for (int cg2 = 0; cg2 < 2; ++cg2) {
                bf16x8 vb = ldb8(vT + ((size_t)((b * Hh + h) * DKh + cg2 * 16 + tl)) * Nn
                                    + m0 + ks * 32 + g * 8);
                oacc[cg2] = __builtin_amdgcn_mfma_f32_16x16x32_bf16(pa, vb, oacc[cg2], 0, 0, 0);
            }
        }
        __syncthreads();
    }

    #pragma unroll
    for (int cg2 = 0; cg2 < 2; ++cg2)
        #pragma unroll
        for (int r = 0; r < 4; ++r) {
            float inv = 1.f / l_run[r];
            o[((size_t)(b * Nn + n0 + w * 16 + g * 4 + r)) * Cc + h * DKh + cg2 * 16 + tl]
                = f2b(oacc[cg2][r] * inv);
        }
}

// ---------------- launch ----------------
extern "C" void kernel_launch(void* const* d_in, const int* in_sizes, int n_in,
                              void* d_out, int out_size, void* d_ws, size_t ws_size,
                              hipStream_t stream)
{
    const float* x   = (const float*)d_in[0];
    const int*   ei  = (const int*)  d_in[1];
    const float* sph = (const float*)d_in[2];
    const float* Wr  = (const float*)d_in[3];
    const float* Wn  = (const float*)d_in[4];
    const float* Wq  = (const float*)d_in[5];
    const float* bq  = (const float*)d_in[6];
    const float* Wk  = (const float*)d_in[7];
    const float* bk  = (const float*)d_in[8];
    const float* Wv  = (const float*)d_in[9];
    const float* bv  = (const float*)d_in[10];
    const float* Wo  = (const float*)d_in[11];
    const float* bo  = (const float*)d_in[12];
    const float* W1  = (const float*)d_in[13];
    const float* b1  = (const float*)d_in[14];
    const float* W2  = (const float*)d_in[15];
    const float* b2  = (const float*)d_in[16];
    const float* g1  = (const float*)d_in[17];
    const float* be1 = (const float*)d_in[18];
    const float* g2  = (const float*)d_in[19];
    const float* be2 = (const float*)d_in[20];
    const float* g3  = (const float*)d_in[21];
    const float* be3 = (const float*)d_in[22];
    float* out = (float*)d_out;

    const size_t SL = (size_t)BNn * Cc;  // 2M elements

    float* ws = (float*)d_ws;
    float* s1 = ws;                  // outsum (fp32)
    float* s2 = s1 + SL;             // h1pre -> h2pre -> out2
    float* s3 = s2 + SL;             // h1
    float* stats = s3 + SL;          // 512 floats

    int* deg    = (int*)(stats + 512);   // 8192
    int* rowst  = deg + 8192;            // 8193 (+pad)
    int* cursor = rowst + 8256;          // 8192
    int* eidx   = cursor + 8192;         // 131072

    unsigned short* xcat = (unsigned short*)(eidx + 131072); // [8192][512] bf16; reused as hid
    unsigned short* qb   = xcat + 2 * SL;                    // [8192][256]
    unsigned short* kb   = qb + SL;                          // reused as osb
    unsigned short* vTb  = kb + SL;
    unsigned short* ob   = vTb + SL;
    unsigned short* osb  = kb;
    unsigned short* hid  = xcat;

    unsigned short* WcatT = ob + SL;          // 256x512
    unsigned short* WqT   = WcatT + 131072;
    unsigned short* WkT   = WqT + 65536;
    unsigned short* WvT   = WkT + 65536;
    unsigned short* WoT   = WvT + 65536;
    unsigned short* W1T   = WoT + 65536;      // 512x256
    unsigned short* W2T   = W1T + 131072;     // 256x512

    dim3 g256(4, 128);
    dim3 g512(8, 128);

    // 0) converts + CSR build + gather
    xconv_k<<<2048, 256, 0, stream>>>(x, xcat);
    wconv_k<<<2560, 256, 0, stream>>>(Wr, Wn, Wq, Wk, Wv, Wo, W1, W2,
                                      WcatT, WqT, WkT, WvT, WoT, W1T, W2T);
    hipMemsetAsync(deg, 0, 8192 * sizeof(int), stream);
    hist_k<<<Ee / 256, 256, 0, stream>>>(ei, deg);
    scan_k<<<1, 256, 0, stream>>>(deg, rowst, cursor);
    place_k<<<Ee / 256, 256, 0, stream>>>(ei, cursor, eidx);
    gather_k<<<BNn, 256, 0, stream>>>(x, rowst, eidx, xcat);

    // 1) h1pre = [x|aggx] @ [Wr;Wn]^T + x   (K=512)
    gemm_mfma_k<<<g256, 256, 0, stream>>>(xcat, WcatT, nullptr, x, nullptr,
                                          s2, nullptr, BNn, 512, 512, Cc, 0, 0);
    // 2) h1 = BN1(h1pre) -> s3
    hipMemsetAsync(stats, 0, 512 * sizeof(float), stream);
    bn_stats_k<<<256, 256, 0, stream>>>(s2, stats, stats + 256);
    bn_apply_k<<<BNn, 256, 0, stream>>>(s2, stats, stats + 256, g1, be1, nullptr, s3, nullptr);
    // 3) q,k,v projections (A = xcat low half, lda=512)
    gemm_mfma_k<<<g256, 256, 0, stream>>>(xcat, WqT, bq, nullptr, nullptr,
                                          nullptr, qb, BNn, Cc, 512, Cc, 0, 0);
    gemm_mfma_k<<<g256, 256, 0, stream>>>(xcat, WkT, bk, nullptr, nullptr,
                                          nullptr, kb, BNn, Cc, 512, Cc, 0, 0);
    gemm_mfma_k<<<g256, 256, 0, stream>>>(xcat, WvT, bv, nullptr, nullptr,
                                          nullptr, vTb, BNn, Cc, 512, Cc, 0, 1);
    // 4) attention -> ob
    attn_k<<<dim3(Hh, Nn / 64, Bg), 256, 0, stream>>>(qb, kb, vTb, sph, ob);
    // 5) h2pre = o @ Wo + bo + x -> s2
    gemm_mfma_k<<<g256, 256, 0, stream>>>(ob, WoT, bo, x, nullptr,
                                          s2, nullptr, BNn, Cc, Cc, Cc, 0, 0);
    // 6) outsum = BN2(h2pre) + h1 -> s1 (fp32) + osb (bf16)
    hipMemsetAsync(stats, 0, 512 * sizeof(float), stream);
    bn_stats_k<<<256, 256, 0, stream>>>(s2, stats, stats + 256);
    bn_apply_k<<<BNn, 256, 0, stream>>>(s2, stats, stats + 256, g2, be2, s3, s1, osb);
    // 7) hidden = relu(outsum @ W1 + b1) -> hid (bf16, stride 512)
    gemm_mfma_k<<<g512, 256, 0, stream>>>(osb, W1T, b1, nullptr, nullptr,
                                          nullptr, hid, BNn, Cc, Cc, 2 * Cc, 1, 0);
    // 8) out2 = hidden @ W2 + b2 + outsum -> s2
    gemm_mfma_k<<<g256, 256, 0, stream>>>(hid, W2T, b2, s1, nullptr,
                                          s2, nullptr, BNn, 2 * Cc, 2 * Cc, Cc, 0, 0);
    // 9) d_out = BN3(out2)
    hipMemsetAsync(stats, 0, 512 * sizeof(float), stream);
    bn_stats_k<<<256, 256, 0, stream>>>(s2, stats, stats + 256);
    bn_apply_k<<<BNn, 256, 0, stream>>>(s2, stats, stats + 256, g3, be3, nullptr, out, nullptr);
}

// Round 5
// 417.312 us; speedup vs baseline: 4.7824x; 1.0085x over previous
//
#include <hip/hip_runtime.h>
#include <hip/hip_bf16.h>

// ---------------- problem constants ----------------
constexpr int Bg  = 8;       // graphs
constexpr int Nn  = 1024;    // nodes per graph
constexpr int Cc  = 256;     // channels
constexpr int Hh  = 8;       // heads
constexpr int DKh = 32;      // head dim
constexpr int Ee  = 131072;  // edges
constexpr int BNn = Bg * Nn; // 8192 total nodes
#define EPSV 1e-5f

typedef __attribute__((ext_vector_type(8))) short bf16x8;
typedef __attribute__((ext_vector_type(4))) float f32x4;

static __device__ __forceinline__ unsigned short f2b(float v) {
    __hip_bfloat16 h = __float2bfloat16(v);
    return __builtin_bit_cast(unsigned short, h);
}
static __device__ __forceinline__ bf16x8 ldb8(const unsigned short* p) {
    return *(const bf16x8*)p;
}

// ---------------- x -> bf16 into xcat[n][0:256] (row stride 512) ----------------
__global__ __launch_bounds__(256) void xconv_k(
    const float* __restrict__ x, unsigned short* __restrict__ xcat)
{
    int i = (blockIdx.x * 256 + threadIdx.x) * 4;
    float4 v = *(const float4*)(x + i);
    int r = i >> 8, c = i & 255;
    unsigned short* d = xcat + (size_t)r * 512 + c;
    d[0] = f2b(v.x); d[1] = f2b(v.y); d[2] = f2b(v.z); d[3] = f2b(v.w);
}

// ---------------- weight transpose+convert ----------------
__global__ __launch_bounds__(256) void wconv_k(
    const float* __restrict__ Wr, const float* __restrict__ Wn,
    const float* __restrict__ Wq, const float* __restrict__ Wk,
    const float* __restrict__ Wv, const float* __restrict__ Wo,
    const float* __restrict__ W1, const float* __restrict__ W2,
    unsigned short* __restrict__ WcatT,
    unsigned short* __restrict__ WqT, unsigned short* __restrict__ WkT,
    unsigned short* __restrict__ WvT, unsigned short* __restrict__ WoT,
    unsigned short* __restrict__ W1T, unsigned short* __restrict__ W2T)
{
    int idx = blockIdx.x * 256 + threadIdx.x;
    if (idx < 131072) {                      // WcatT [256][512]
        int n = idx >> 9, k = idx & 511;
        float v = (k < 256) ? Wr[k * 256 + n] : Wn[(k - 256) * 256 + n];
        WcatT[(size_t)n * 512 + k] = f2b(v);
    } else if (idx < 393216) {               // q,k,v,o
        int l = idx - 131072;
        int wsel = l >> 16; l &= 65535;
        int n = l >> 8, kk = l & 255;
        const float* S = wsel == 0 ? Wq : wsel == 1 ? Wk : wsel == 2 ? Wv : Wo;
        unsigned short* D = wsel == 0 ? WqT : wsel == 1 ? WkT : wsel == 2 ? WvT : WoT;
        D[n * 256 + kk] = f2b(S[kk * 256 + n]);
    } else if (idx < 524288) {               // W1 [256][512] -> W1T [512][256]
        int l = idx - 393216;
        int n = l >> 8, kk = l & 255;
        W1T[l] = f2b(W1[kk * 512 + n]);
    } else {                                 // W2 [512][256] -> W2T [256][512]
        int l = idx - 524288;
        int n = l >> 9, kk = l & 511;
        W2T[l] = f2b(W2[kk * 256 + n]);
    }
}

// ---------------- CSR build ----------------
__global__ __launch_bounds__(256) void hist_k(
    const int* __restrict__ ei, int* __restrict__ deg)
{
    int e = blockIdx.x * 256 + threadIdx.x;
    atomicAdd(&deg[ei[Ee + e]], 1);
}

__global__ __launch_bounds__(256) void scan_k(
    const int* __restrict__ deg, int* __restrict__ rowst, int* __restrict__ cursor)
{
    __shared__ int partial[256];
    int t = threadIdx.x;
    int local[32];
    int s = 0;
    #pragma unroll
    for (int i = 0; i < 32; ++i) { local[i] = deg[t * 32 + i]; s += local[i]; }
    partial[t] = s;
    __syncthreads();
    for (int off = 1; off < 256; off <<= 1) {
        int v = (t >= off) ? partial[t - off] : 0;
        __syncthreads();
        partial[t] += v;
        __syncthreads();
    }
    int base = partial[t] - s;
    #pragma unroll
    for (int i = 0; i < 32; ++i) {
        int idx = t * 32 + i;
        rowst[idx] = base;
        cursor[idx] = base;
        base += local[i];
    }
    if (t == 255) rowst[8192] = base;
}

__global__ __launch_bounds__(256) void place_k(
    const int* __restrict__ ei, int* __restrict__ cursor, int* __restrict__ eidx)
{
    int e = blockIdx.x * 256 + threadIdx.x;
    int s = ei[e], d = ei[Ee + e];
    int pos = atomicAdd(&cursor[d], 1);
    eidx[pos] = s;
}

// ---------------- gather: aggx[n] = sum_{e: dst=n} x[src_e] ----------------
__global__ __launch_bounds__(256) void gather_k(
    const float* __restrict__ x, const int* __restrict__ rowst,
    const int* __restrict__ eidx, unsigned short* __restrict__ xcat)
{
    int n = blockIdx.x, c = threadIdx.x;
    int b0 = rowst[n], b1 = rowst[n + 1];
    float acc = 0.f;
    for (int i = b0; i < b1; ++i) {
        int s = eidx[i];
        acc += x[(size_t)s * Cc + c];
    }
    xcat[(size_t)n * 512 + 256 + c] = f2b(acc);
}

// ---------------- MFMA GEMM ----------------
__global__ __launch_bounds__(256) void gemm_mfma_k(
    const unsigned short* __restrict__ A, const unsigned short* __restrict__ WT,
    const float* __restrict__ bias, const float* __restrict__ add1,
    const float* __restrict__ add2, float* __restrict__ outf,
    unsigned short* __restrict__ outb,
    int M, int K, int lda, int N, int relu, int vtrans)
{
    const int t = threadIdx.x;
    const int wave = t >> 6, lane = t & 63;
    const int tl = lane & 15, g = lane >> 4;
    const int wr = wave >> 1, wc = wave & 1;
    const int m0 = blockIdx.y * 64, n0 = blockIdx.x * 64;

    f32x4 acc[2][2] = {};

    const unsigned short* a0 = A  + (size_t)(m0 + wr * 32 + tl) * lda + g * 8;
    const unsigned short* a1 = a0 + (size_t)16 * lda;
    const unsigned short* b0 = WT + (size_t)(n0 + wc * 32 + tl) * K + g * 8;
    const unsigned short* b1 = b0 + (size_t)16 * K;

    for (int k0 = 0; k0 < K; k0 += 32) {
        bf16x8 af0 = ldb8(a0 + k0), af1 = ldb8(a1 + k0);
        bf16x8 bf0 = ldb8(b0 + k0), bf1 = ldb8(b1 + k0);
        acc[0][0] = __builtin_amdgcn_mfma_f32_16x16x32_bf16(af0, bf0, acc[0][0], 0, 0, 0);
        acc[0][1] = __builtin_amdgcn_mfma_f32_16x16x32_bf16(af0, bf1, acc[0][1], 0, 0, 0);
        acc[1][0] = __builtin_amdgcn_mfma_f32_16x16x32_bf16(af1, bf0, acc[1][0], 0, 0, 0);
        acc[1][1] = __builtin_amdgcn_mfma_f32_16x16x32_bf16(af1, bf1, acc[1][1], 0, 0, 0);
    }

    #pragma unroll
    for (int r16 = 0; r16 < 2; ++r16)
        #pragma unroll
        for (int c16 = 0; c16 < 2; ++c16)
            #pragma unroll
            for (int reg = 0; reg < 4; ++reg) {
                int row = m0 + wr * 32 + r16 * 16 + g * 4 + reg;
                int col = n0 + wc * 32 + c16 * 16 + tl;
                float v = acc[r16][c16][reg];
                if (bias) v += bias[col];
                size_t idx = (size_t)row * N + col;
                if (add1) v += add1[idx];
                if (add2) v += add2[idx];
                if (relu) v = fmaxf(v, 0.f);
                if (outf) outf[idx] = v;
                if (outb) {
                    if (vtrans) {
                        int bg = row >> 10, n = row & 1023;
                        int hh = col >> 5,  d = col & 31;
                        outb[((size_t)((bg * Hh + hh) * DKh + d)) * Nn + n] = f2b(v);
                    } else {
                        outb[idx] = f2b(v);
                    }
                }
            }
}

// ---------------- BN stats ----------------
__global__ __launch_bounds__(256) void bn_stats_k(
    const float* __restrict__ h, float* __restrict__ gsum, float* __restrict__ gsq)
{
    int ch = threadIdx.x;
    int r0 = blockIdx.x * 32;
    float s = 0.f, s2 = 0.f;
    for (int r = r0; r < r0 + 32; ++r) {
        float v = h[(size_t)r * Cc + ch];
        s += v; s2 += v * v;
    }
    atomicAdd(&gsum[ch], s);
    atomicAdd(&gsq[ch], s2);
}

// ---------------- BN apply ----------------
__global__ __launch_bounds__(256) void bn_apply_k(
    const float* __restrict__ h, const float* __restrict__ gsum,
    const float* __restrict__ gsq, const float* __restrict__ gamma,
    const float* __restrict__ beta, const float* __restrict__ add,
    float* __restrict__ outf, unsigned short* __restrict__ outb)
{
    size_t idx = (size_t)blockIdx.x * 256 + threadIdx.x;
    int ch = (int)(idx & (Cc - 1));
    float m   = gsum[ch] * (1.f / BNn);
    float var = gsq[ch] * (1.f / BNn) - m * m;
    float sc  = rsqrtf(var + EPSV) * gamma[ch];
    float v = (h[idx] - m) * sc + beta[ch];
    if (add) v += add[idx];
    if (outf) outf[idx] = v;
    if (outb) outb[idx] = f2b(v);
}

// ---------------- MFMA flash attention, all heads per block ----------------
// grid (Nn/16, Bg), 512 threads = 8 waves; wave w = head w, block owns Q rows
// n0..n0+15 for ALL heads. sph 16x64 fp32 tile staged in LDS once per m-tile
// (8x traffic cut vs per-head blocks). P LDS round-trip is wave-private.
__global__ __launch_bounds__(512) void attn_k(
    const unsigned short* __restrict__ q, const unsigned short* __restrict__ k,
    const unsigned short* __restrict__ vT, const float* __restrict__ sph,
    unsigned short* __restrict__ o)
{
    const int n0 = blockIdx.x * 16;
    const int b  = blockIdx.y;
    const int t  = threadIdx.x;
    const int w  = t >> 6;          // wave = head
    const int lane = t & 63;
    const int tl = lane & 15, g = lane >> 4;

    __shared__ float Sph[16][65];               // sph tile, +1 pad
    __shared__ unsigned short Ps[Hh][16][72];   // per-wave P tile (bf16)

    const float scale = 0.17677669529663687f;   // 1/sqrt(32)

    // Q A-fragment: q-row = n0+tl, k-dim = g*8..g*8+7 of head w
    bf16x8 qa = ldb8(q + ((size_t)(b * Nn + n0 + tl)) * Cc + w * DKh + g * 8);

    float m_run[4], l_run[4];
    f32x4 oacc[2] = {};
    #pragma unroll
    for (int r = 0; r < 4; ++r) { m_run[r] = -1e30f; l_run[r] = 0.f; }

    for (int m0 = 0; m0 < Nn; m0 += 64) {
        __syncthreads();   // prev iter's Sph reads complete
        // stage sph tile: 1024 floats, 2 per thread, coalesced
        {
            int l1 = t, l2 = t + 512;
            Sph[l1 >> 6][l1 & 63] = sph[((size_t)b * Nn + n0 + (l1 >> 6)) * Nn + m0 + (l1 & 63)];
            Sph[l2 >> 6][l2 & 63] = sph[((size_t)b * Nn + n0 + (l2 >> 6)) * Nn + m0 + (l2 & 63)];
        }
        __syncthreads();   // Sph ready

        // scores: 4 col-groups of 16 (K=32 in one MFMA each)
        f32x4 s[4];
        #pragma unroll
        for (int cg = 0; cg < 4; ++cg) {
            bf16x8 kb = ldb8(k + ((size_t)(b * Nn + m0 + cg * 16 + tl)) * Cc + w * DKh + g * 8);
            f32x4 z = {0.f, 0.f, 0.f, 0.f};
            s[cg] = __builtin_amdgcn_mfma_f32_16x16x32_bf16(qa, kb, z, 0, 0, 0);
        }

        // sph modulation from LDS (C-layout: row g*4+r, col cg*16+tl)
        float sv[4][4];
        #pragma unroll
        for (int cg = 0; cg < 4; ++cg)
            #pragma unroll
            for (int r = 0; r < 4; ++r)
                sv[cg][r] = s[cg][r] * scale * Sph[g * 4 + r][cg * 16 + tl];

        // online softmax
        float tmax[4];
        #pragma unroll
        for (int r = 0; r < 4; ++r)
            tmax[r] = fmaxf(fmaxf(sv[0][r], sv[1][r]), fmaxf(sv[2][r], sv[3][r]));
        #pragma unroll
        for (int off = 1; off < 16; off <<= 1)
            #pragma unroll
            for (int r = 0; r < 4; ++r)
                tmax[r] = fmaxf(tmax[r], __shfl_xor(tmax[r], off));

        float alpha[4], tsum[4];
        #pragma unroll
        for (int r = 0; r < 4; ++r) {
            float nm = fmaxf(m_run[r], tmax[r]);
            alpha[r] = __expf(m_run[r] - nm);
            m_run[r] = nm;
            float rs = 0.f;
            #pragma unroll
            for (int cg = 0; cg < 4; ++cg) {
                float p = __expf(sv[cg][r] - nm);
                Ps[w][g * 4 + r][cg * 16 + tl] = f2b(p);
                rs += p;
            }
            tsum[r] = rs;
        }
        #pragma unroll
        for (int off = 1; off < 16; off <<= 1)
            #pragma unroll
            for (int r = 0; r < 4; ++r)
                tsum[r] += __shfl_xor(tsum[r], off);
        #pragma unroll
        for (int r = 0; r < 4; ++r)
            l_run[r] = l_run[r] * alpha[r] + tsum[r];

        #pragma unroll
        for (int cg2 = 0; cg2 < 2; ++cg2)
            #pragma unroll
            for (int r = 0; r < 4; ++r)
                oacc[cg2][r] *= alpha[r];

        // PV: O[16x32] += P[16x64] @ V[64x32]; Ps is wave-private (no barrier)
        #pragma unroll
        for (int ks = 0; ks < 2; ++ks) {
            bf16x8 pa = ldb8(&Ps[w][tl][ks * 32 + g * 8]);
            #pragma unroll
            for (int cg2 = 0; cg2 < 2; ++cg2) {
                bf16x8 vb = ldb8(vT + ((size_t)((b * Hh + w) * DKh + cg2 * 16 + tl)) * Nn
                                    + m0 + ks * 32 + g * 8);
                oacc[cg2] = __builtin_amdgcn_mfma_f32_16x16x32_bf16(pa, vb, oacc[cg2], 0, 0, 0);
            }
        }
    }

    // write O (bf16, feeds Wo GEMM)
    #pragma unroll
    for (int cg2 = 0; cg2 < 2; ++cg2)
        #pragma unroll
        for (int r = 0; r < 4; ++r) {
            float inv = 1.f / l_run[r];
            o[((size_t)(b * Nn + n0 + g * 4 + r)) * Cc + w * DKh + cg2 * 16 + tl]
                = f2b(oacc[cg2][r] * inv);
        }
}

// ---------------- launch ----------------
extern "C" void kernel_launch(void* const* d_in, const int* in_sizes, int n_in,
                              void* d_out, int out_size, void* d_ws, size_t ws_size,
                              hipStream_t stream)
{
    const float* x   = (const float*)d_in[0];
    const int*   ei  = (const int*)  d_in[1];
    const float* sph = (const float*)d_in[2];
    const float* Wr  = (const float*)d_in[3];
    const float* Wn  = (const float*)d_in[4];
    const float* Wq  = (const float*)d_in[5];
    const float* bq  = (const float*)d_in[6];
    const float* Wk  = (const float*)d_in[7];
    const float* bk  = (const float*)d_in[8];
    const float* Wv  = (const float*)d_in[9];
    const float* bv  = (const float*)d_in[10];
    const float* Wo  = (const float*)d_in[11];
    const float* bo  = (const float*)d_in[12];
    const float* W1  = (const float*)d_in[13];
    const float* b1  = (const float*)d_in[14];
    const float* W2  = (const float*)d_in[15];
    const float* b2  = (const float*)d_in[16];
    const float* g1  = (const float*)d_in[17];
    const float* be1 = (const float*)d_in[18];
    const float* g2  = (const float*)d_in[19];
    const float* be2 = (const float*)d_in[20];
    const float* g3  = (const float*)d_in[21];
    const float* be3 = (const float*)d_in[22];
    float* out = (float*)d_out;

    const size_t SL = (size_t)BNn * Cc;  // 2M elements

    float* ws = (float*)d_ws;
    float* s1 = ws;                  // outsum (fp32)
    float* s2 = s1 + SL;             // h1pre -> h2pre -> out2
    float* s3 = s2 + SL;             // h1
    float* stats = s3 + SL;          // 512 floats

    int* deg    = (int*)(stats + 512);
    int* rowst  = deg + 8192;
    int* cursor = rowst + 8256;
    int* eidx   = cursor + 8192;

    unsigned short* xcat = (unsigned short*)(eidx + 131072); // [8192][512]; reused as hid
    unsigned short* qb   = xcat + 2 * SL;
    unsigned short* kb   = qb + SL;                          // reused as osb
    unsigned short* vTb  = kb + SL;
    unsigned short* ob   = vTb + SL;
    unsigned short* osb  = kb;
    unsigned short* hid  = xcat;

    unsigned short* WcatT = ob + SL;          // 256x512
    unsigned short* WqT   = WcatT + 131072;
    unsigned short* WkT   = WqT + 65536;
    unsigned short* WvT   = WkT + 65536;
    unsigned short* WoT   = WvT + 65536;
    unsigned short* W1T   = WoT + 65536;
    unsigned short* W2T   = W1T + 131072;

    dim3 g256(4, 128);
    dim3 g512(8, 128);

    // 0) converts + CSR build + gather
    xconv_k<<<2048, 256, 0, stream>>>(x, xcat);
    wconv_k<<<2560, 256, 0, stream>>>(Wr, Wn, Wq, Wk, Wv, Wo, W1, W2,
                                      WcatT, WqT, WkT, WvT, WoT, W1T, W2T);
    hipMemsetAsync(deg, 0, 8192 * sizeof(int), stream);
    hist_k<<<Ee / 256, 256, 0, stream>>>(ei, deg);
    scan_k<<<1, 256, 0, stream>>>(deg, rowst, cursor);
    place_k<<<Ee / 256, 256, 0, stream>>>(ei, cursor, eidx);
    gather_k<<<BNn, 256, 0, stream>>>(x, rowst, eidx, xcat);

    // 1) h1pre = [x|aggx] @ [Wr;Wn]^T + x   (K=512)
    gemm_mfma_k<<<g256, 256, 0, stream>>>(xcat, WcatT, nullptr, x, nullptr,
                                          s2, nullptr, BNn, 512, 512, Cc, 0, 0);
    // 2) h1 = BN1(h1pre) -> s3
    hipMemsetAsync(stats, 0, 512 * sizeof(float), stream);
    bn_stats_k<<<256, 256, 0, stream>>>(s2, stats, stats + 256);
    bn_apply_k<<<BNn, 256, 0, stream>>>(s2, stats, stats + 256, g1, be1, nullptr, s3, nullptr);
    // 3) q,k,v projections (A = xcat low half, lda=512)
    gemm_mfma_k<<<g256, 256, 0, stream>>>(xcat, WqT, bq, nullptr, nullptr,
                                          nullptr, qb, BNn, Cc, 512, Cc, 0, 0);
    gemm_mfma_k<<<g256, 256, 0, stream>>>(xcat, WkT, bk, nullptr, nullptr,
                                          nullptr, kb, BNn, Cc, 512, Cc, 0, 0);
    gemm_mfma_k<<<g256, 256, 0, stream>>>(xcat, WvT, bv, nullptr, nullptr,
                                          nullptr, vTb, BNn, Cc, 512, Cc, 0, 1);
    // 4) attention -> ob
    attn_k<<<dim3(Nn / 16, Bg), 512, 0, stream>>>(qb, kb, vTb, sph, ob);
    // 5) h2pre = o @ Wo + bo + x -> s2
    gemm_mfma_k<<<g256, 256, 0, stream>>>(ob, WoT, bo, x, nullptr,
                                          s2, nullptr, BNn, Cc, Cc, Cc, 0, 0);
    // 6) outsum = BN2(h2pre) + h1 -> s1 (fp32) + osb (bf16)
    hipMemsetAsync(stats, 0, 512 * sizeof(float), stream);
    bn_stats_k<<<256, 256, 0, stream>>>(s2, stats, stats + 256);
    bn_apply_k<<<BNn, 256, 0, stream>>>(s2, stats, stats + 256, g2, be2, s3, s1, osb);
    // 7) hidden = relu(outsum @ W1 + b1) -> hid (bf16)
    gemm_mfma_k<<<g512, 256, 0, stream>>>(osb, W1T, b1, nullptr, nullptr,
                                          nullptr, hid, BNn, Cc, Cc, 2 * Cc, 1, 0);
    // 8) out2 = hidden @ W2 + b2 + outsum -> s2
    gemm_mfma_k<<<g256, 256, 0, stream>>>(hid, W2T, b2, s1, nullptr,
                                          s2, nullptr, BNn, 2 * Cc, 2 * Cc, Cc, 0, 0);
    // 9) d_out = BN3(out2)
    hipMemsetAsync(stats, 0, 512 * sizeof(float), stream);
    bn_stats_k<<<256, 256, 0, stream>>>(s2, stats, stats + 256);
    bn_apply_k<<<BNn, 256, 0, stream>>>(s2, stats, stats + 256, g3, be3, nullptr, out, nullptr);
}